// Round 5
// baseline (1250.907 us; speedup 1.0000x reference)
//
#include <hip/hip_runtime.h>
#include <math.h>

#define HID    128
#define IN_CH  271
#define SEQ    281
#define NCLS   1854
#define BATCH  256
#define M_TOT  (SEQ * BATCH)          // 71936 = 562 * 128
#define KPAD0  288                    // 271 padded to 9*32
#define KPAD1  128

typedef __attribute__((ext_vector_type(8))) short short8;
typedef __attribute__((ext_vector_type(4))) float floatx4;

__device__ __forceinline__ unsigned short f2bf(float f) {
    union { float f; unsigned u; } v; v.f = f;
    unsigned u = v.u;
    u += 0x7FFF + ((u >> 16) & 1);        // RNE
    return (unsigned short)(u >> 16);
}

__device__ __forceinline__ float fast_sigmoid(float s) {
    return 1.f / (1.f + __expf(-s));
}
__device__ __forceinline__ float fast_tanh(float s) {
    float a = fabsf(s);
    float e = __expf(-2.f * a);
    float t = (1.f - e) / (1.f + e);
    return copysignf(t, s);
}

// ---------------------------------------------------------------------------
// Transpose+convert X: X[b][k][t] fp32 -> Abf[(b*281+t)*288 + k] bf16.
// ---------------------------------------------------------------------------
__global__ __launch_bounds__(256) void xt_kernel(
    const float* __restrict__ X, unsigned short* __restrict__ Abf)
{
    const int tb = blockIdx.x;            // 0..4, t-tile of 64
    const int b  = blockIdx.y;
    const int tid = threadIdx.x;
    const int t0 = tb * 64;
    const float* __restrict__ Xb = X + (size_t)b * (IN_CH * SEQ);

    __shared__ float Xl[32][65];

    for (int kc = 0; kc < KPAD0 / 32; ++kc) {
#pragma unroll
        for (int r = 0; r < 8; ++r) {
            int e = tid + 256 * r;
            int kk = e >> 6, tt = e & 63;
            int k = kc * 32 + kk, t = t0 + tt;
            Xl[kk][tt] = (k < IN_CH && t < SEQ) ? Xb[k * SEQ + t] : 0.f;
        }
        __syncthreads();
        {
            int tt = tid >> 2, part = tid & 3;
            int t = t0 + tt;
            if (t < SEQ) {
                union { unsigned short s[8]; uint4 v; } u;
#pragma unroll
                for (int i = 0; i < 8; ++i) u.s[i] = f2bf(Xl[part * 8 + i][tt]);
                *(uint4*)(Abf + ((size_t)b * SEQ + t) * KPAD0 + kc * 32 + part * 8) = u.v;
            }
        }
        __syncthreads();
    }
}

// ---------------------------------------------------------------------------
// Weight transpose+convert.
// blk 0..5  : x-part rows -> Wt0/Wt1 images [n][Kpad] bf16 (for gemm_xg)
// blk 6..11 : recurrent rows -> Wh0/Wh1 images [gate*128+n][128] bf16 (for gru)
// grid (12, 32), blockIdx.y = n-slice of 4.
// ---------------------------------------------------------------------------
__global__ __launch_bounds__(256) void wt_kernel(
    const float* __restrict__ Wr0, const float* __restrict__ Wu0, const float* __restrict__ Wo0,
    const float* __restrict__ Wr1, const float* __restrict__ Wu1, const float* __restrict__ Wo1,
    unsigned short* __restrict__ Wt0, unsigned short* __restrict__ Wt1,
    unsigned short* __restrict__ Wh0, unsigned short* __restrict__ Wh1)
{
    const int blk = blockIdx.x;
    const int tid = threadIdx.x;
    const int n0  = blockIdx.y * 4;

    if (blk < 6) {
        const int layer = blk / 3, g = blk % 3;
        const float* __restrict__ W =
            (layer == 0) ? ((g == 0) ? Wr0 : (g == 1) ? Wu0 : Wo0)
                         : ((g == 0) ? Wr1 : (g == 1) ? Wu1 : Wo1);
        const int Kp   = (layer == 0) ? KPAD0 : KPAD1;
        const int Ksrc = (layer == 0) ? IN_CH : HID;
        unsigned short* __restrict__ out =
            (layer == 0) ? (Wt0 + (size_t)g * HID * KPAD0) : (Wt1 + (size_t)g * HID * KPAD1);
        for (int n = n0; n < n0 + 4; ++n)
            for (int k = tid; k < Kp; k += 256) {
                float v = (k < Ksrc) ? W[(size_t)k * HID + n] : 0.f;
                out[(size_t)n * Kp + k] = f2bf(v);
            }
    } else {
        const int layer = (blk - 6) / 3, g = (blk - 6) % 3;
        const float* __restrict__ W =
            (layer == 0) ? ((g == 0) ? Wr0 : (g == 1) ? Wu0 : Wo0)
                         : ((g == 0) ? Wr1 : (g == 1) ? Wu1 : Wo1);
        const int base = (layer == 0) ? IN_CH : HID;
        unsigned short* __restrict__ out =
            ((layer == 0) ? Wh0 : Wh1) + (size_t)g * HID * HID;
        for (int n = n0; n < n0 + 4; ++n)
            for (int k = tid; k < HID; k += 256)
                out[(size_t)n * HID + k] = f2bf(W[(size_t)(base + k) * HID + n]);
    }
}

// ---------------------------------------------------------------------------
// bf16 MFMA GEMM: out rows are T-MAJOR: XG[t*BATCH+b][g*128+n] where the
// A-row index m = b*SEQ + t.  XG val = sum_k A[m][k]*Wt[g][n][k] + bias_g[n]
// ---------------------------------------------------------------------------
__global__ __launch_bounds__(256) void gemm_xg(
    const unsigned short* __restrict__ A,
    const unsigned short* __restrict__ Wt,
    const float* __restrict__ br, const float* __restrict__ bu, const float* __restrict__ bo,
    float* __restrict__ XG, int Kpad)
{
    const int g = blockIdx.y;
    const float* __restrict__ bias = (g == 0) ? br : (g == 1) ? bu : bo;
    const unsigned short* __restrict__ B = Wt + (size_t)g * HID * Kpad;

    __shared__ unsigned short As[128 * 40];
    __shared__ unsigned short Bs[128 * 40];

    const int tid   = threadIdx.x;
    const int lane  = tid & 63;
    const int wave  = tid >> 6;
    const int l15   = lane & 15;
    const int quad  = lane >> 4;
    const int mhalf = wave >> 1;
    const int nhalf = wave & 1;
    const size_t m0 = (size_t)blockIdx.x * 128;

    floatx4 acc[4][4];
#pragma unroll
    for (int im = 0; im < 4; ++im)
#pragma unroll
        for (int in = 0; in < 4; ++in) acc[im][in] = (floatx4)0.f;

    const int r0 = tid >> 2, p0 = tid & 3;
    const int r1 = (tid + 256) >> 2, p1 = tid & 3;

    const int ksteps = Kpad >> 5;
    for (int kt = 0; kt < ksteps; ++kt) {
        if (kt) __syncthreads();
        const int kb = kt * 32;
        uint4 va0 = *(const uint4*)(A + (m0 + r0) * Kpad + kb + p0 * 8);
        uint4 va1 = *(const uint4*)(A + (m0 + r1) * Kpad + kb + p1 * 8);
        uint4 vb0 = *(const uint4*)(B + (size_t)r0 * Kpad + kb + p0 * 8);
        uint4 vb1 = *(const uint4*)(B + (size_t)r1 * Kpad + kb + p1 * 8);
        *(uint4*)(As + r0 * 40 + p0 * 8) = va0;
        *(uint4*)(As + r1 * 40 + p1 * 8) = va1;
        *(uint4*)(Bs + r0 * 40 + p0 * 8) = vb0;
        *(uint4*)(Bs + r1 * 40 + p1 * 8) = vb1;
        __syncthreads();

        short8 af[4], bf[4];
#pragma unroll
        for (int im = 0; im < 4; ++im)
            af[im] = *(const short8*)(As + (mhalf * 64 + im * 16 + l15) * 40 + quad * 8);
#pragma unroll
        for (int in = 0; in < 4; ++in)
            bf[in] = *(const short8*)(Bs + (nhalf * 64 + in * 16 + l15) * 40 + quad * 8);
#pragma unroll
        for (int im = 0; im < 4; ++im)
#pragma unroll
            for (int in = 0; in < 4; ++in)
                acc[im][in] = __builtin_amdgcn_mfma_f32_16x16x32_bf16(
                    af[im], bf[in], acc[im][in], 0, 0, 0);
    }

    float bv[4];
#pragma unroll
    for (int in = 0; in < 4; ++in) bv[in] = bias[nhalf * 64 + in * 16 + l15];
#pragma unroll
    for (int im = 0; im < 4; ++im) {
#pragma unroll
        for (int v = 0; v < 4; ++v) {
            unsigned m = (unsigned)m0 + mhalf * 64 + im * 16 + quad * 4 + v;
            unsigned bb = m / SEQ;            // batch
            unsigned tt = m - bb * SEQ;       // time
            float* row = XG + ((size_t)tt * BATCH + bb) * 384 + g * HID;
#pragma unroll
            for (int in = 0; in < 4; ++in)
                row[nhalf * 64 + in * 16 + l15] = acc[im][in][v] + bv[in];
        }
    }
}

// ---------------------------------------------------------------------------
// MFMA GRU recurrence. 16 batch elements per block, 16 blocks, 256 threads
// (4 waves, 1/SIMD). Per step: [16x128] @ [128x384] via mfma 16x16x32 bf16.
// Wave w owns n-tiles {2w,2w+1} of each gate -> r/u/o columns match, so the
// h-update is wave-local. Weight B-fragments (96 regs) hoisted out of the
// t-loop: MFMA reads them from VGPR/AGPR natively (no shuttle cost).
// h state: fp32 in registers (C-layout) + bf16 LDS image for next-step
// A-frags. rh: C->LDS(bf16)->A round trip. 2 barriers/step. xg prefetched
// one step ahead (XG rows are t-major).
// ---------------------------------------------------------------------------
template <int LAYER>
__global__ __launch_bounds__(256, 1) void gru_mfma(
    const unsigned short* __restrict__ Wh,    // [384][128] bf16: gate*128+n rows
    const float* __restrict__ XG,             // [t*BATCH+b][384] fp32
    unsigned short* __restrict__ H0bf,        // LAYER=0 out: [b*SEQ+t][128] bf16
    float* __restrict__ H1fin)                // LAYER=1 out: [b][128] fp32
{
    const int b0   = blockIdx.x * 16;
    const int tid  = threadIdx.x;
    const int w    = tid >> 6;
    const int lane = tid & 63;
    const int l15  = lane & 15;
    const int quad = lane >> 4;

    __shared__ unsigned short Hbf[16 * 136];
    __shared__ unsigned short Rbf[16 * 136];

    // hoist weight B-fragments: 6 tiles x 4 k-steps, tile rows n = T*16+l15
    short8 Br[2][4], Bu[2][4], Bo[2][4];
#pragma unroll
    for (int t2 = 0; t2 < 2; ++t2)
#pragma unroll
        for (int kk = 0; kk < 4; ++kk) {
            Br[t2][kk] = *(const short8*)(Wh + (size_t)((2*w + t2)      * 16 + l15) * HID + kk * 32 + quad * 8);
            Bu[t2][kk] = *(const short8*)(Wh + (size_t)((8 + 2*w + t2) * 16 + l15) * HID + kk * 32 + quad * 8);
            Bo[t2][kk] = *(const short8*)(Wh + (size_t)((16 + 2*w + t2)* 16 + l15) * HID + kk * 32 + quad * 8);
        }

    for (int idx = tid; idx < 16 * 136; idx += 256) { Hbf[idx] = 0; Rbf[idx] = 0; }

    // fp32 h for this wave's columns: col(t2) = 32w + t2*16 + l15, rows quad*4+i
    float hcur[2][4];
#pragma unroll
    for (int t2 = 0; t2 < 2; ++t2)
#pragma unroll
        for (int i = 0; i < 4; ++i) hcur[t2][i] = 0.f;

    const int colw = 32 * w + l15;

    // xg for t=0
    float xr[2][4], xu[2][4], xo[2][4];
    {
        const float* __restrict__ xg0 = XG + ((size_t)0 * BATCH + b0) * 384;
#pragma unroll
        for (int t2 = 0; t2 < 2; ++t2)
#pragma unroll
            for (int i = 0; i < 4; ++i) {
                const int row = quad * 4 + i;
                const int c = colw + t2 * 16;
                xr[t2][i] = xg0[row * 384 + c];
                xu[t2][i] = xg0[row * 384 + 128 + c];
                xo[t2][i] = xg0[row * 384 + 256 + c];
            }
    }
    __syncthreads();

    for (int t = 0; t < SEQ; ++t) {
        // prefetch xg(t+1)
        float nr[2][4], nu[2][4], no[2][4];
        {
            const int tn = (t + 1 < SEQ) ? t + 1 : t;
            const float* __restrict__ xgn = XG + ((size_t)tn * BATCH + b0) * 384;
#pragma unroll
            for (int t2 = 0; t2 < 2; ++t2)
#pragma unroll
                for (int i = 0; i < 4; ++i) {
                    const int row = quad * 4 + i;
                    const int c = colw + t2 * 16;
                    nr[t2][i] = xgn[row * 384 + c];
                    nu[t2][i] = xgn[row * 384 + 128 + c];
                    no[t2][i] = xgn[row * 384 + 256 + c];
                }
        }

        // ---- phase 1: r,u MFMAs over K=128
        floatx4 accr[2], accu[2];
        accr[0] = (floatx4)0.f; accr[1] = (floatx4)0.f;
        accu[0] = (floatx4)0.f; accu[1] = (floatx4)0.f;
#pragma unroll
        for (int kk = 0; kk < 4; ++kk) {
            short8 a = *(const short8*)(Hbf + l15 * 136 + kk * 32 + quad * 8);
            accr[0] = __builtin_amdgcn_mfma_f32_16x16x32_bf16(a, Br[0][kk], accr[0], 0, 0, 0);
            accr[1] = __builtin_amdgcn_mfma_f32_16x16x32_bf16(a, Br[1][kk], accr[1], 0, 0, 0);
            accu[0] = __builtin_amdgcn_mfma_f32_16x16x32_bf16(a, Bu[0][kk], accu[0], 0, 0, 0);
            accu[1] = __builtin_amdgcn_mfma_f32_16x16x32_bf16(a, Bu[1][kk], accu[1], 0, 0, 0);
        }

        // gates r,u; write rh image
        float ug[2][4];
#pragma unroll
        for (int t2 = 0; t2 < 2; ++t2)
#pragma unroll
            for (int i = 0; i < 4; ++i) {
                float rg = fast_sigmoid(accr[t2][i] + xr[t2][i]);
                ug[t2][i] = fast_sigmoid(accu[t2][i] + xu[t2][i]);
                const int row = quad * 4 + i;
                Rbf[row * 136 + colw + t2 * 16] = f2bf(rg * hcur[t2][i]);
            }
        __syncthreads();

        // ---- phase 2: o MFMAs over rh
        floatx4 acco[2];
        acco[0] = (floatx4)0.f; acco[1] = (floatx4)0.f;
#pragma unroll
        for (int kk = 0; kk < 4; ++kk) {
            short8 a = *(const short8*)(Rbf + l15 * 136 + kk * 32 + quad * 8);
            acco[0] = __builtin_amdgcn_mfma_f32_16x16x32_bf16(a, Bo[0][kk], acco[0], 0, 0, 0);
            acco[1] = __builtin_amdgcn_mfma_f32_16x16x32_bf16(a, Bo[1][kk], acco[1], 0, 0, 0);
        }

        // h update + publish
#pragma unroll
        for (int t2 = 0; t2 < 2; ++t2)
#pragma unroll
            for (int i = 0; i < 4; ++i) {
                float og = fast_tanh(acco[t2][i] + xo[t2][i]);
                float hn = hcur[t2][i] + ug[t2][i] * (og - hcur[t2][i]);
                hcur[t2][i] = hn;
                const int row = quad * 4 + i;
                const int c = colw + t2 * 16;
                unsigned short hb = f2bf(hn);
                Hbf[row * 136 + c] = hb;
                if (LAYER == 0)
                    H0bf[((size_t)(b0 + row) * SEQ + t) * HID + c] = hb;
                xr[t2][i] = nr[t2][i]; xu[t2][i] = nu[t2][i]; xo[t2][i] = no[t2][i];
            }
        __syncthreads();
    }

    if (LAYER == 1) {
#pragma unroll
        for (int t2 = 0; t2 < 2; ++t2)
#pragma unroll
            for (int i = 0; i < 4; ++i) {
                const int row = quad * 4 + i;
                H1fin[(size_t)(b0 + row) * HID + colw + t2 * 16] = hcur[t2][i];
            }
    }
}

// ---------------------------------------------------------------------------
// Classifier: out[b][c] = bfc[c] + sum_k H1[b][k] * Wfc[k][c]
// ---------------------------------------------------------------------------
__global__ __launch_bounds__(256) void cls_kernel(
    const float* __restrict__ H1, const float* __restrict__ Wfc,
    const float* __restrict__ bfc, float* __restrict__ out)
{
    const int b = blockIdx.x;
    const int tid = threadIdx.x;
    __shared__ float h[HID];
    if (tid < HID) h[tid] = H1[(size_t)b * HID + tid];
    __syncthreads();
    for (int c = tid; c < NCLS; c += 256) {
        float a = bfc[c];
#pragma unroll 8
        for (int k = 0; k < HID; ++k)
            a += h[k] * Wfc[(size_t)k * NCLS + c];
        out[(size_t)b * NCLS + c] = a;
    }
}

// ---------------------------------------------------------------------------
extern "C" void kernel_launch(void* const* d_in, const int* in_sizes, int n_in,
                              void* d_out, int out_size, void* d_ws, size_t ws_size,
                              hipStream_t stream)
{
    const float* X   = (const float*)d_in[0];
    const float* Wr0 = (const float*)d_in[1];
    const float* br0 = (const float*)d_in[2];
    const float* Wu0 = (const float*)d_in[3];
    const float* bu0 = (const float*)d_in[4];
    const float* Wo0 = (const float*)d_in[5];
    const float* bo0 = (const float*)d_in[6];
    const float* Wr1 = (const float*)d_in[7];
    const float* br1 = (const float*)d_in[8];
    const float* Wu1 = (const float*)d_in[9];
    const float* bu1 = (const float*)d_in[10];
    const float* Wo1 = (const float*)d_in[11];
    const float* bo1 = (const float*)d_in[12];
    const float* Wfc = (const float*)d_in[13];
    const float* bfc = (const float*)d_in[14];
    float* out = (float*)d_out;

    // workspace layout:
    //   XG fp32 [M_TOT*384]        110,493,696 B
    //   Abf bf16 [M_TOT*288]        41,435,136 B  (H0bf and H1fin alias here)
    //   Wt0 bf16 [3*128*288]           221,184 B
    //   Wt1 bf16 [3*128*128]            98,304 B
    //   Wh0 bf16 [384*128]              98,304 B
    //   Wh1 bf16 [384*128]              98,304 B
    char* ws = (char*)d_ws;
    float*          XG   = (float*)ws;
    unsigned short* Abf  = (unsigned short*)(ws + (size_t)M_TOT * 384 * 4);
    unsigned short* H0bf = Abf;                 // alias: Abf dead after gemm l0
    float*          H1fin= (float*)Abf;         // alias: H0bf dead after gemm l1
    unsigned short* Wt0  = (unsigned short*)(ws + (size_t)M_TOT * 384 * 4 + (size_t)M_TOT * KPAD0 * 2);
    unsigned short* Wt1  = Wt0 + (size_t)3 * HID * KPAD0;
    unsigned short* Wh0  = Wt1 + (size_t)3 * HID * KPAD1;
    unsigned short* Wh1  = Wh0 + (size_t)384 * HID;

    wt_kernel<<<dim3(12, 32), 256, 0, stream>>>(Wr0, Wu0, Wo0, Wr1, Wu1, Wo1, Wt0, Wt1, Wh0, Wh1);
    xt_kernel<<<dim3(5, BATCH), 256, 0, stream>>>(X, Abf);
    gemm_xg  <<<dim3(M_TOT / 128, 3), 256, 0, stream>>>(Abf, Wt0, br0, bu0, bo0, XG, KPAD0);
    gru_mfma<0><<<dim3(16), 256, 0, stream>>>(Wh0, XG, H0bf, nullptr);
    gemm_xg  <<<dim3(M_TOT / 128, 3), 256, 0, stream>>>(H0bf, Wt1, br1, bu1, bo1, XG, KPAD1);
    gru_mfma<1><<<dim3(16), 256, 0, stream>>>(Wh1, XG, nullptr, H1fin);
    cls_kernel<<<dim3(BATCH), 256, 0, stream>>>(H1fin, Wfc, bfc, out);
}

// Round 6
// 1016.910 us; speedup vs baseline: 1.2301x; 1.2301x over previous
//
#include <hip/hip_runtime.h>
#include <math.h>

#define HID    128
#define IN_CH  271
#define SEQ    281
#define NCLS   1854
#define BATCH  256
#define M_TOT  (SEQ * BATCH)          // 71936 = 562 * 128
#define KPAD0  288                    // 271 padded to 9*32
#define KPAD1  128

typedef __attribute__((ext_vector_type(8))) short short8;
typedef __attribute__((ext_vector_type(4))) float floatx4;

__device__ __forceinline__ unsigned short f2bf(float f) {
    union { float f; unsigned u; } v; v.f = f;
    unsigned u = v.u;
    u += 0x7FFF + ((u >> 16) & 1);        // RNE
    return (unsigned short)(u >> 16);
}

__device__ __forceinline__ float fast_sigmoid(float s) {
    return 1.f / (1.f + __expf(-s));
}
__device__ __forceinline__ float fast_tanh(float s) {
    float a = fabsf(s);
    float e = __expf(-2.f * a);
    float t = (1.f - e) / (1.f + e);
    return copysignf(t, s);
}

// LDS-only barrier: waits ds-ops (lgkmcnt) but does NOT drain vmcnt, so
// in-flight global loads/stores keep flying across the sync (CK block_sync_lds).
__device__ __forceinline__ void sync_lds() {
    asm volatile("s_waitcnt lgkmcnt(0)\n\ts_barrier" ::: "memory");
}

// ---------------------------------------------------------------------------
// Transpose+convert X: X[b][k][t] fp32 -> Abf[(b*281+t)*288 + k] bf16.
// ---------------------------------------------------------------------------
__global__ __launch_bounds__(256) void xt_kernel(
    const float* __restrict__ X, unsigned short* __restrict__ Abf)
{
    const int tb = blockIdx.x;            // 0..4, t-tile of 64
    const int b  = blockIdx.y;
    const int tid = threadIdx.x;
    const int t0 = tb * 64;
    const float* __restrict__ Xb = X + (size_t)b * (IN_CH * SEQ);

    __shared__ float Xl[32][65];

    for (int kc = 0; kc < KPAD0 / 32; ++kc) {
#pragma unroll
        for (int r = 0; r < 8; ++r) {
            int e = tid + 256 * r;
            int kk = e >> 6, tt = e & 63;
            int k = kc * 32 + kk, t = t0 + tt;
            Xl[kk][tt] = (k < IN_CH && t < SEQ) ? Xb[k * SEQ + t] : 0.f;
        }
        __syncthreads();
        {
            int tt = tid >> 2, part = tid & 3;
            int t = t0 + tt;
            if (t < SEQ) {
                union { unsigned short s[8]; uint4 v; } u;
#pragma unroll
                for (int i = 0; i < 8; ++i) u.s[i] = f2bf(Xl[part * 8 + i][tt]);
                *(uint4*)(Abf + ((size_t)b * SEQ + t) * KPAD0 + kc * 32 + part * 8) = u.v;
            }
        }
        __syncthreads();
    }
}

// ---------------------------------------------------------------------------
// Weight transpose+convert.
// blk 0..5  : x-part rows -> Wt0/Wt1 images [n][Kpad] bf16 (for gemm_xg)
// blk 6..11 : recurrent rows -> Wh0/Wh1 images [gate*128+n][128] bf16 (gru)
// ---------------------------------------------------------------------------
__global__ __launch_bounds__(256) void wt_kernel(
    const float* __restrict__ Wr0, const float* __restrict__ Wu0, const float* __restrict__ Wo0,
    const float* __restrict__ Wr1, const float* __restrict__ Wu1, const float* __restrict__ Wo1,
    unsigned short* __restrict__ Wt0, unsigned short* __restrict__ Wt1,
    unsigned short* __restrict__ Wh0, unsigned short* __restrict__ Wh1)
{
    const int blk = blockIdx.x;
    const int tid = threadIdx.x;
    const int n0  = blockIdx.y * 4;

    if (blk < 6) {
        const int layer = blk / 3, g = blk % 3;
        const float* __restrict__ W =
            (layer == 0) ? ((g == 0) ? Wr0 : (g == 1) ? Wu0 : Wo0)
                         : ((g == 0) ? Wr1 : (g == 1) ? Wu1 : Wo1);
        const int Kp   = (layer == 0) ? KPAD0 : KPAD1;
        const int Ksrc = (layer == 0) ? IN_CH : HID;
        unsigned short* __restrict__ out =
            (layer == 0) ? (Wt0 + (size_t)g * HID * KPAD0) : (Wt1 + (size_t)g * HID * KPAD1);
        for (int n = n0; n < n0 + 4; ++n)
            for (int k = tid; k < Kp; k += 256) {
                float v = (k < Ksrc) ? W[(size_t)k * HID + n] : 0.f;
                out[(size_t)n * Kp + k] = f2bf(v);
            }
    } else {
        const int layer = (blk - 6) / 3, g = (blk - 6) % 3;
        const float* __restrict__ W =
            (layer == 0) ? ((g == 0) ? Wr0 : (g == 1) ? Wu0 : Wo0)
                         : ((g == 0) ? Wr1 : (g == 1) ? Wu1 : Wo1);
        const int base = (layer == 0) ? IN_CH : HID;
        unsigned short* __restrict__ out =
            ((layer == 0) ? Wh0 : Wh1) + (size_t)g * HID * HID;
        for (int n = n0; n < n0 + 4; ++n)
            for (int k = tid; k < HID; k += 256)
                out[(size_t)n * HID + k] = f2bf(W[(size_t)(base + k) * HID + n]);
    }
}

// ---------------------------------------------------------------------------
// bf16 MFMA GEMM: out rows are T-MAJOR: XG[t*BATCH+b][g*128+n] where the
// A-row index m = b*SEQ + t.  XG val = sum_k A[m][k]*Wt[g][n][k] + bias_g[n]
// ---------------------------------------------------------------------------
__global__ __launch_bounds__(256) void gemm_xg(
    const unsigned short* __restrict__ A,
    const unsigned short* __restrict__ Wt,
    const float* __restrict__ br, const float* __restrict__ bu, const float* __restrict__ bo,
    float* __restrict__ XG, int Kpad)
{
    const int g = blockIdx.y;
    const float* __restrict__ bias = (g == 0) ? br : (g == 1) ? bu : bo;
    const unsigned short* __restrict__ B = Wt + (size_t)g * HID * Kpad;

    __shared__ unsigned short As[128 * 40];
    __shared__ unsigned short Bs[128 * 40];

    const int tid   = threadIdx.x;
    const int lane  = tid & 63;
    const int wave  = tid >> 6;
    const int l15   = lane & 15;
    const int quad  = lane >> 4;
    const int mhalf = wave >> 1;
    const int nhalf = wave & 1;
    const size_t m0 = (size_t)blockIdx.x * 128;

    floatx4 acc[4][4];
#pragma unroll
    for (int im = 0; im < 4; ++im)
#pragma unroll
        for (int in = 0; in < 4; ++in) acc[im][in] = (floatx4)0.f;

    const int r0 = tid >> 2, p0 = tid & 3;
    const int r1 = (tid + 256) >> 2, p1 = tid & 3;

    const int ksteps = Kpad >> 5;
    for (int kt = 0; kt < ksteps; ++kt) {
        if (kt) __syncthreads();
        const int kb = kt * 32;
        uint4 va0 = *(const uint4*)(A + (m0 + r0) * Kpad + kb + p0 * 8);
        uint4 va1 = *(const uint4*)(A + (m0 + r1) * Kpad + kb + p1 * 8);
        uint4 vb0 = *(const uint4*)(B + (size_t)r0 * Kpad + kb + p0 * 8);
        uint4 vb1 = *(const uint4*)(B + (size_t)r1 * Kpad + kb + p1 * 8);
        *(uint4*)(As + r0 * 40 + p0 * 8) = va0;
        *(uint4*)(As + r1 * 40 + p1 * 8) = va1;
        *(uint4*)(Bs + r0 * 40 + p0 * 8) = vb0;
        *(uint4*)(Bs + r1 * 40 + p1 * 8) = vb1;
        __syncthreads();

        short8 af[4], bf[4];
#pragma unroll
        for (int im = 0; im < 4; ++im)
            af[im] = *(const short8*)(As + (mhalf * 64 + im * 16 + l15) * 40 + quad * 8);
#pragma unroll
        for (int in = 0; in < 4; ++in)
            bf[in] = *(const short8*)(Bs + (nhalf * 64 + in * 16 + l15) * 40 + quad * 8);
#pragma unroll
        for (int im = 0; im < 4; ++im)
#pragma unroll
            for (int in = 0; in < 4; ++in)
                acc[im][in] = __builtin_amdgcn_mfma_f32_16x16x32_bf16(
                    af[im], bf[in], acc[im][in], 0, 0, 0);
    }

    float bv[4];
#pragma unroll
    for (int in = 0; in < 4; ++in) bv[in] = bias[nhalf * 64 + in * 16 + l15];
#pragma unroll
    for (int im = 0; im < 4; ++im) {
#pragma unroll
        for (int v = 0; v < 4; ++v) {
            unsigned m = (unsigned)m0 + mhalf * 64 + im * 16 + quad * 4 + v;
            unsigned bb = m / SEQ;            // batch
            unsigned tt = m - bb * SEQ;       // time
            float* row = XG + ((size_t)tt * BATCH + bb) * 384 + g * HID;
#pragma unroll
            for (int in = 0; in < 4; ++in)
                row[nhalf * 64 + in * 16 + l15] = acc[im][in][v] + bv[in];
        }
    }
}

// ---------------------------------------------------------------------------
// MFMA GRU recurrence. 16 batch rows per block, 16 blocks, 512 threads
// (8 waves, 2/SIMD). Per step: [16x128] @ [128x384] via mfma 16x16x32 bf16.
// Wave w owns n-tile w of EACH gate (cols 16w..16w+15) -> h-update is
// wave-local. Weight B-fragments (48 VGPRs) hoisted out of the t-loop as
// MFMA operands (AGPR-resident, read natively). h: fp32 in registers
// (C-layout) + bf16 LDS image for next step's A-frags; rh via LDS round
// trip. 2 LDS-ONLY barriers/step (no vmcnt drain!) -> xg loads (prefetched
// one step ahead) and H0bf stores stay in flight across the sync.
// ---------------------------------------------------------------------------
template <int LAYER>
__global__ __launch_bounds__(512, 1) void gru_mfma(
    const unsigned short* __restrict__ Wh,    // [384][128] bf16: gate*128+n rows
    const float* __restrict__ XG,             // [t*BATCH+b][384] fp32
    unsigned short* __restrict__ H0bf,        // LAYER=0 out: [b*SEQ+t][128] bf16
    float* __restrict__ H1fin)                // LAYER=1 out: [b][128] fp32
{
    const int b0   = blockIdx.x * 16;
    const int tid  = threadIdx.x;
    const int w    = tid >> 6;        // 0..7
    const int lane = tid & 63;
    const int l15  = lane & 15;
    const int quad = lane >> 4;

    __shared__ unsigned short Hbf[16 * 136];
    __shared__ unsigned short Rbf[16 * 136];

    // hoisted weight B-fragments: one 16-col tile per gate, 4 k-steps
    short8 Br[4], Bu[4], Bo[4];
#pragma unroll
    for (int kk = 0; kk < 4; ++kk) {
        Br[kk] = *(const short8*)(Wh + (size_t)(        w * 16 + l15) * HID + kk * 32 + quad * 8);
        Bu[kk] = *(const short8*)(Wh + (size_t)(128 +   w * 16 + l15) * HID + kk * 32 + quad * 8);
        Bo[kk] = *(const short8*)(Wh + (size_t)(256 +   w * 16 + l15) * HID + kk * 32 + quad * 8);
    }

    for (int idx = tid; idx < 16 * 136; idx += 512) { Hbf[idx] = 0; Rbf[idx] = 0; }

    const int c = w * 16 + l15;       // this thread's h-column, 0..127
    float hcur[4];                    // batch rows quad*4+i
#pragma unroll
    for (int i = 0; i < 4; ++i) hcur[i] = 0.f;

    // xg for t=0
    float xr[4], xu[4], xo[4];
    {
        const float* __restrict__ xg0 = XG + ((size_t)0 * BATCH + b0) * 384;
#pragma unroll
        for (int i = 0; i < 4; ++i) {
            const int row = quad * 4 + i;
            xr[i] = xg0[row * 384 + c];
            xu[i] = xg0[row * 384 + 128 + c];
            xo[i] = xg0[row * 384 + 256 + c];
        }
    }
    __syncthreads();

    for (int t = 0; t < SEQ; ++t) {
        // prefetch xg(t+1) — lands while this step computes
        float nr[4], nu[4], no[4];
        {
            const int tn = (t + 1 < SEQ) ? t + 1 : t;
            const float* __restrict__ xgn = XG + ((size_t)tn * BATCH + b0) * 384;
#pragma unroll
            for (int i = 0; i < 4; ++i) {
                const int row = quad * 4 + i;
                nr[i] = xgn[row * 384 + c];
                nu[i] = xgn[row * 384 + 128 + c];
                no[i] = xgn[row * 384 + 256 + c];
            }
        }

        // ---- phase 1: r,u MFMAs over K=128
        floatx4 accr = (floatx4)0.f, accu = (floatx4)0.f;
#pragma unroll
        for (int kk = 0; kk < 4; ++kk) {
            short8 a = *(const short8*)(Hbf + l15 * 136 + kk * 32 + quad * 8);
            accr = __builtin_amdgcn_mfma_f32_16x16x32_bf16(a, Br[kk], accr, 0, 0, 0);
            accu = __builtin_amdgcn_mfma_f32_16x16x32_bf16(a, Bu[kk], accu, 0, 0, 0);
        }

        float ug[4];
#pragma unroll
        for (int i = 0; i < 4; ++i) {
            float rg = fast_sigmoid(accr[i] + xr[i]);
            ug[i] = fast_sigmoid(accu[i] + xu[i]);
            Rbf[(quad * 4 + i) * 136 + c] = f2bf(rg * hcur[i]);
        }
        sync_lds();

        // ---- phase 2: o MFMAs over rh
        floatx4 acco = (floatx4)0.f;
#pragma unroll
        for (int kk = 0; kk < 4; ++kk) {
            short8 a = *(const short8*)(Rbf + l15 * 136 + kk * 32 + quad * 8);
            acco = __builtin_amdgcn_mfma_f32_16x16x32_bf16(a, Bo[kk], acco, 0, 0, 0);
        }

#pragma unroll
        for (int i = 0; i < 4; ++i) {
            float og = fast_tanh(acco[i] + xo[i]);
            float hn = hcur[i] + ug[i] * (og - hcur[i]);
            hcur[i] = hn;
            const int row = quad * 4 + i;
            unsigned short hb = f2bf(hn);
            Hbf[row * 136 + c] = hb;
            if (LAYER == 0)
                H0bf[((size_t)(b0 + row) * SEQ + t) * HID + c] = hb;
            xr[i] = nr[i]; xu[i] = nu[i]; xo[i] = no[i];
        }
        sync_lds();
    }

    if (LAYER == 1) {
#pragma unroll
        for (int i = 0; i < 4; ++i)
            H1fin[(size_t)(b0 + quad * 4 + i) * HID + c] = hcur[i];
    }
}

// ---------------------------------------------------------------------------
// Classifier: out[b][c] = bfc[c] + sum_k H1[b][k] * Wfc[k][c]
// ---------------------------------------------------------------------------
__global__ __launch_bounds__(256) void cls_kernel(
    const float* __restrict__ H1, const float* __restrict__ Wfc,
    const float* __restrict__ bfc, float* __restrict__ out)
{
    const int b = blockIdx.x;
    const int tid = threadIdx.x;
    __shared__ float h[HID];
    if (tid < HID) h[tid] = H1[(size_t)b * HID + tid];
    __syncthreads();
    for (int c = tid; c < NCLS; c += 256) {
        float a = bfc[c];
#pragma unroll 8
        for (int k = 0; k < HID; ++k)
            a += h[k] * Wfc[(size_t)k * NCLS + c];
        out[(size_t)b * NCLS + c] = a;
    }
}

// ---------------------------------------------------------------------------
extern "C" void kernel_launch(void* const* d_in, const int* in_sizes, int n_in,
                              void* d_out, int out_size, void* d_ws, size_t ws_size,
                              hipStream_t stream)
{
    const float* X   = (const float*)d_in[0];
    const float* Wr0 = (const float*)d_in[1];
    const float* br0 = (const float*)d_in[2];
    const float* Wu0 = (const float*)d_in[3];
    const float* bu0 = (const float*)d_in[4];
    const float* Wo0 = (const float*)d_in[5];
    const float* bo0 = (const float*)d_in[6];
    const float* Wr1 = (const float*)d_in[7];
    const float* br1 = (const float*)d_in[8];
    const float* Wu1 = (const float*)d_in[9];
    const float* bu1 = (const float*)d_in[10];
    const float* Wo1 = (const float*)d_in[11];
    const float* bo1 = (const float*)d_in[12];
    const float* Wfc = (const float*)d_in[13];
    const float* bfc = (const float*)d_in[14];
    float* out = (float*)d_out;

    char* ws = (char*)d_ws;
    float*          XG   = (float*)ws;                                         // 110.5 MB
    unsigned short* Abf  = (unsigned short*)(ws + (size_t)M_TOT * 384 * 4);    //  41.4 MB
    unsigned short* H0bf = Abf;                 // alias: Abf dead after gemm l0
    float*          H1fin= (float*)Abf;         // alias: H0bf dead after gemm l1
    unsigned short* Wt0  = (unsigned short*)(ws + (size_t)M_TOT * 384 * 4 + (size_t)M_TOT * KPAD0 * 2);
    unsigned short* Wt1  = Wt0 + (size_t)3 * HID * KPAD0;
    unsigned short* Wh0  = Wt1 + (size_t)3 * HID * KPAD1;
    unsigned short* Wh1  = Wh0 + (size_t)384 * HID;

    wt_kernel<<<dim3(12, 32), 256, 0, stream>>>(Wr0, Wu0, Wo0, Wr1, Wu1, Wo1, Wt0, Wt1, Wh0, Wh1);
    xt_kernel<<<dim3(5, BATCH), 256, 0, stream>>>(X, Abf);
    gemm_xg  <<<dim3(M_TOT / 128, 3), 256, 0, stream>>>(Abf, Wt0, br0, bu0, bo0, XG, KPAD0);
    gru_mfma<0><<<dim3(16), 512, 0, stream>>>(Wh0, XG, H0bf, nullptr);
    gemm_xg  <<<dim3(M_TOT / 128, 3), 256, 0, stream>>>(H0bf, Wt1, br1, bu1, bo1, XG, KPAD1);
    gru_mfma<1><<<dim3(16), 512, 0, stream>>>(Wh1, XG, nullptr, H1fin);
    cls_kernel<<<dim3(BATCH), 256, 0, stream>>>(H1fin, Wfc, bfc, out);
}

// Round 7
// 764.337 us; speedup vs baseline: 1.6366x; 1.3304x over previous
//
#include <hip/hip_runtime.h>
#include <math.h>

#define HID    128
#define IN_CH  271
#define SEQ    281
#define NCLS   1854
#define BATCH  256
#define M_TOT  (SEQ * BATCH)          // 71936 = 562 * 128
#define KPAD0  288                    // 271 padded to 9*32

typedef __attribute__((ext_vector_type(8))) short short8;
typedef __attribute__((ext_vector_type(4))) float floatx4;

__device__ __forceinline__ unsigned short f2bf(float f) {
    union { float f; unsigned u; } v; v.f = f;
    unsigned u = v.u;
    u += 0x7FFF + ((u >> 16) & 1);        // RNE
    return (unsigned short)(u >> 16);
}

// fast reciprocal: v_rcp_f32 (~1e-7 rel err), avoids the ~10-instr exact div
__device__ __forceinline__ float fast_rcp(float x) {
    float r;
    asm("v_rcp_f32 %0, %1" : "=v"(r) : "v"(x));
    return r;
}
__device__ __forceinline__ float fast_sigmoid(float s) {
    return fast_rcp(1.f + __expf(-s));
}
__device__ __forceinline__ float fast_tanh(float s) {
    float a = fabsf(s);
    float e = __expf(-2.f * a);
    float t = (1.f - e) * fast_rcp(1.f + e);
    return copysignf(t, s);
}

// LDS-only barrier: waits ds-ops but does NOT drain vmcnt — global loads/
// stores stay in flight across the sync.
__device__ __forceinline__ void sync_lds() {
    asm volatile("s_waitcnt lgkmcnt(0)\n\ts_barrier" ::: "memory");
}

// ---------------------------------------------------------------------------
// Transpose+convert X: X[b][k][t] fp32 -> Abf[(b*281+t)*288 + k] bf16.
// ---------------------------------------------------------------------------
__global__ __launch_bounds__(256) void xt_kernel(
    const float* __restrict__ X, unsigned short* __restrict__ Abf)
{
    const int tb = blockIdx.x;            // 0..4, t-tile of 64
    const int b  = blockIdx.y;
    const int tid = threadIdx.x;
    const int t0 = tb * 64;
    const float* __restrict__ Xb = X + (size_t)b * (IN_CH * SEQ);

    __shared__ float Xl[32][65];

    for (int kc = 0; kc < KPAD0 / 32; ++kc) {
#pragma unroll
        for (int r = 0; r < 8; ++r) {
            int e = tid + 256 * r;
            int kk = e >> 6, tt = e & 63;
            int k = kc * 32 + kk, t = t0 + tt;
            Xl[kk][tt] = (k < IN_CH && t < SEQ) ? Xb[k * SEQ + t] : 0.f;
        }
        __syncthreads();
        {
            int tt = tid >> 2, part = tid & 3;
            int t = t0 + tt;
            if (t < SEQ) {
                union { unsigned short s[8]; uint4 v; } u;
#pragma unroll
                for (int i = 0; i < 8; ++i) u.s[i] = f2bf(Xl[part * 8 + i][tt]);
                *(uint4*)(Abf + ((size_t)b * SEQ + t) * KPAD0 + kc * 32 + part * 8) = u.v;
            }
        }
        __syncthreads();
    }
}

// ---------------------------------------------------------------------------
// Weight transpose+convert. grid (12, 32), blockIdx.y = n-slice of 4.
// blk 0..2 : Wt0 [n][288]        = W0g[k][n], k<271 (gemm B, layer0 x-part)
// blk 3..5 : Wh0 [g*128+n][128]  = W0g[271+k][n]     (gru, layer0 h-part)
// blk 6..8 : Wx1 [g*128+n][128]  = W1g[k][n]         (gru, layer1 x-part)
// blk 9..11: Wh1 [g*128+n][128]  = W1g[128+k][n]     (gru, layer1 h-part)
// ---------------------------------------------------------------------------
__global__ __launch_bounds__(256) void wt_kernel(
    const float* __restrict__ Wr0, const float* __restrict__ Wu0, const float* __restrict__ Wo0,
    const float* __restrict__ Wr1, const float* __restrict__ Wu1, const float* __restrict__ Wo1,
    unsigned short* __restrict__ Wt0, unsigned short* __restrict__ Wh0,
    unsigned short* __restrict__ Wx1, unsigned short* __restrict__ Wh1)
{
    const int blk  = blockIdx.x;
    const int kind = blk / 3, g = blk % 3;
    const int tid  = threadIdx.x;
    const int n0   = blockIdx.y * 4;

    const float* __restrict__ W =
        (kind <= 1) ? ((g == 0) ? Wr0 : (g == 1) ? Wu0 : Wo0)
                    : ((g == 0) ? Wr1 : (g == 1) ? Wu1 : Wo1);

    if (kind == 0) {
        unsigned short* __restrict__ out = Wt0 + (size_t)g * HID * KPAD0;
        for (int n = n0; n < n0 + 4; ++n)
            for (int k = tid; k < KPAD0; k += 256) {
                float v = (k < IN_CH) ? W[(size_t)k * HID + n] : 0.f;
                out[(size_t)n * KPAD0 + k] = f2bf(v);
            }
    } else {
        const int rbase = (kind == 1) ? IN_CH : (kind == 2) ? 0 : HID;
        unsigned short* __restrict__ out =
            ((kind == 1) ? Wh0 : (kind == 2) ? Wx1 : Wh1) + (size_t)g * HID * HID;
        for (int n = n0; n < n0 + 4; ++n)
            for (int k = tid; k < HID; k += 256)
                out[(size_t)n * HID + k] = f2bf(W[(size_t)(rbase + k) * HID + n]);
    }
}

// ---------------------------------------------------------------------------
// bf16 MFMA GEMM (layer-0 x-contributions only).
// Logical row m' = t*256 + b; tile m0 = blk*128 -> tt = m0>>8, b0m = m0&255.
// A storage rows are b*SEQ+t (xt layout); staging reads 64B-coalesced.
// Output: XG[(tt*384 + g*128 + n)*256 + b]  (fp32), float4 stores.
// ---------------------------------------------------------------------------
__global__ __launch_bounds__(256) void gemm_xg(
    const unsigned short* __restrict__ A,
    const unsigned short* __restrict__ Wt,
    const float* __restrict__ br, const float* __restrict__ bu, const float* __restrict__ bo,
    float* __restrict__ XG)
{
    const int g = blockIdx.y;
    const float* __restrict__ bias = (g == 0) ? br : (g == 1) ? bu : bo;
    const unsigned short* __restrict__ B = Wt + (size_t)g * HID * KPAD0;

    __shared__ unsigned short As[128 * 40];
    __shared__ unsigned short Bs[128 * 40];

    const int tid   = threadIdx.x;
    const int lane  = tid & 63;
    const int wave  = tid >> 6;
    const int l15   = lane & 15;
    const int quad  = lane >> 4;
    const int mhalf = wave >> 1;
    const int nhalf = wave & 1;
    const int m0    = blockIdx.x * 128;
    const int tt    = m0 >> 8;
    const int b0m   = m0 & 255;

    floatx4 acc[4][4];
#pragma unroll
    for (int im = 0; im < 4; ++im)
#pragma unroll
        for (int in = 0; in < 4; ++in) acc[im][in] = (floatx4)0.f;

    const int r0 = tid >> 2, p0 = tid & 3;
    const int r1 = (tid + 256) >> 2, p1 = tid & 3;

    for (int kt = 0; kt < KPAD0 / 32; ++kt) {
        if (kt) __syncthreads();
        const int kb = kt * 32;
        uint4 va0 = *(const uint4*)(A + ((size_t)(b0m + r0) * SEQ + tt) * KPAD0 + kb + p0 * 8);
        uint4 va1 = *(const uint4*)(A + ((size_t)(b0m + r1) * SEQ + tt) * KPAD0 + kb + p1 * 8);
        uint4 vb0 = *(const uint4*)(B + (size_t)r0 * KPAD0 + kb + p0 * 8);
        uint4 vb1 = *(const uint4*)(B + (size_t)r1 * KPAD0 + kb + p1 * 8);
        *(uint4*)(As + r0 * 40 + p0 * 8) = va0;
        *(uint4*)(As + r1 * 40 + p1 * 8) = va1;
        *(uint4*)(Bs + r0 * 40 + p0 * 8) = vb0;
        *(uint4*)(Bs + r1 * 40 + p1 * 8) = vb1;
        __syncthreads();

        short8 af[4], bf[4];
#pragma unroll
        for (int im = 0; im < 4; ++im)
            af[im] = *(const short8*)(As + (mhalf * 64 + im * 16 + l15) * 40 + quad * 8);
#pragma unroll
        for (int in = 0; in < 4; ++in)
            bf[in] = *(const short8*)(Bs + (nhalf * 64 + in * 16 + l15) * 40 + quad * 8);
#pragma unroll
        for (int im = 0; im < 4; ++im)
#pragma unroll
            for (int in = 0; in < 4; ++in)
                acc[im][in] = __builtin_amdgcn_mfma_f32_16x16x32_bf16(
                    af[im], bf[in], acc[im][in], 0, 0, 0);
    }

    float bv[4];
#pragma unroll
    for (int in = 0; in < 4; ++in) bv[in] = bias[nhalf * 64 + in * 16 + l15];
#pragma unroll
    for (int im = 0; im < 4; ++im) {
        const int bb = b0m + mhalf * 64 + im * 16 + quad * 4;
#pragma unroll
        for (int in = 0; in < 4; ++in) {
            const int n = nhalf * 64 + in * 16 + l15;
            float4 v = make_float4(acc[im][in][0] + bv[in], acc[im][in][1] + bv[in],
                                   acc[im][in][2] + bv[in], acc[im][in][3] + bv[in]);
            *(float4*)(XG + ((size_t)tt * 384 + g * HID + n) * BATCH + bb) = v;
        }
    }
}

// ---------------------------------------------------------------------------
// FUSED 2-layer GRU recurrence. 16 batch rows/block, 16 blocks, 512 threads
// (8 waves, 2/SIMD). Wave w owns cols 16w..16w+15 of every gate of BOTH
// layers. All weight B-fragments (Wh0, Wx1, Wh1 = 144 regs) hoisted as MFMA
// operands. Layer-1 x-part = h0(t) @ Wx1 via MFMA against the h0 LDS image
// (no global H0, no second GEMM pass). 3 LDS-only barriers/step:
//   P1 (r0,u0) B  P2 (o0, h0-update) B  P3 (xg1 + r1,u1) B  P4 (o1, h1-update)
// P4->P1 needs no barrier (P1 touches only Hbf0-read/Rbf0-write; both safe).
// xg(t+1) prefetched as 3x dwordx4 (XG is [t][chan][b]).
// ---------------------------------------------------------------------------
__global__ __launch_bounds__(512, 1) void gru_fused(
    const unsigned short* __restrict__ Wh0,
    const unsigned short* __restrict__ Wx1,
    const unsigned short* __restrict__ Wh1,
    const float* __restrict__ XG,
    const float* __restrict__ br1, const float* __restrict__ bu1, const float* __restrict__ bo1,
    float* __restrict__ H1fin)
{
    const int b0   = blockIdx.x * 16;
    const int tid  = threadIdx.x;
    const int w    = tid >> 6;        // 0..7
    const int lane = tid & 63;
    const int l15  = lane & 15;
    const int quad = lane >> 4;
    const int c    = w * 16 + l15;    // this thread's column 0..127

    __shared__ unsigned short Hbf0[16 * 136];
    __shared__ unsigned short Rbf0[16 * 136];
    __shared__ unsigned short Hbf1[16 * 136];
    __shared__ unsigned short Rbf1[16 * 136];

    // hoisted weight B-fragments: 9 (layer,gate) tiles x 4 k-steps
    short8 B0r[4], B0u[4], B0o[4], Bxr[4], Bxu[4], Bxo[4], B1r[4], B1u[4], B1o[4];
#pragma unroll
    for (int kk = 0; kk < 4; ++kk) {
        const size_t off = (size_t)(w * 16 + l15) * HID + kk * 32 + quad * 8;
        B0r[kk] = *(const short8*)(Wh0 + off);
        B0u[kk] = *(const short8*)(Wh0 + (size_t)128 * HID + off);
        B0o[kk] = *(const short8*)(Wh0 + (size_t)256 * HID + off);
        Bxr[kk] = *(const short8*)(Wx1 + off);
        Bxu[kk] = *(const short8*)(Wx1 + (size_t)128 * HID + off);
        Bxo[kk] = *(const short8*)(Wx1 + (size_t)256 * HID + off);
        B1r[kk] = *(const short8*)(Wh1 + off);
        B1u[kk] = *(const short8*)(Wh1 + (size_t)128 * HID + off);
        B1o[kk] = *(const short8*)(Wh1 + (size_t)256 * HID + off);
    }

    for (int idx = tid; idx < 16 * 136; idx += 512) {
        Hbf0[idx] = 0; Rbf0[idx] = 0; Hbf1[idx] = 0; Rbf1[idx] = 0;
    }

    float h0c[4], h1c[4];
#pragma unroll
    for (int i = 0; i < 4; ++i) { h0c[i] = 0.f; h1c[i] = 0.f; }

    const float br1c = br1[c], bu1c = bu1[c], bo1c = bo1[c];

    // xg(0): 3 vector loads, rows b0+quad*4..+3
    float4 xr4, xu4, xo4;
    {
        const float* p = XG + ((size_t)0 * 384 + c) * BATCH + b0 + quad * 4;
        xr4 = *(const float4*)(p);
        xu4 = *(const float4*)(p + (size_t)128 * BATCH);
        xo4 = *(const float4*)(p + (size_t)256 * BATCH);
    }
    __syncthreads();

    for (int t = 0; t < SEQ; ++t) {
        // prefetch xg(t+1)
        float4 nr4, nu4, no4;
        {
            const int tn = (t + 1 < SEQ) ? t + 1 : t;
            const float* p = XG + ((size_t)tn * 384 + c) * BATCH + b0 + quad * 4;
            nr4 = *(const float4*)(p);
            nu4 = *(const float4*)(p + (size_t)128 * BATCH);
            no4 = *(const float4*)(p + (size_t)256 * BATCH);
        }

        // ---- P1: layer0 r,u
        floatx4 ar = (floatx4)0.f, au = (floatx4)0.f;
#pragma unroll
        for (int kk = 0; kk < 4; ++kk) {
            short8 a = *(const short8*)(Hbf0 + l15 * 136 + kk * 32 + quad * 8);
            ar = __builtin_amdgcn_mfma_f32_16x16x32_bf16(a, B0r[kk], ar, 0, 0, 0);
            au = __builtin_amdgcn_mfma_f32_16x16x32_bf16(a, B0u[kk], au, 0, 0, 0);
        }
        float ug0[4];
#pragma unroll
        for (int i = 0; i < 4; ++i) {
            float rg = fast_sigmoid(ar[i] + xr4[i]);
            ug0[i] = fast_sigmoid(au[i] + xu4[i]);
            Rbf0[(quad * 4 + i) * 136 + c] = f2bf(rg * h0c[i]);
        }
        sync_lds();

        // ---- P2: layer0 o + h0 update
        floatx4 ao = (floatx4)0.f;
#pragma unroll
        for (int kk = 0; kk < 4; ++kk) {
            short8 a = *(const short8*)(Rbf0 + l15 * 136 + kk * 32 + quad * 8);
            ao = __builtin_amdgcn_mfma_f32_16x16x32_bf16(a, B0o[kk], ao, 0, 0, 0);
        }
#pragma unroll
        for (int i = 0; i < 4; ++i) {
            float og = fast_tanh(ao[i] + xo4[i]);
            h0c[i] = h0c[i] + ug0[i] * (og - h0c[i]);
            Hbf0[(quad * 4 + i) * 136 + c] = f2bf(h0c[i]);
        }
        sync_lds();

        // ---- P3: layer1 xg (from h0(t)) + r,u (from h1(t-1))
        floatx4 a1r = (floatx4)0.f, a1u = (floatx4)0.f, axo = (floatx4)0.f;
#pragma unroll
        for (int kk = 0; kk < 4; ++kk) {
            short8 a0 = *(const short8*)(Hbf0 + l15 * 136 + kk * 32 + quad * 8);
            a1r = __builtin_amdgcn_mfma_f32_16x16x32_bf16(a0, Bxr[kk], a1r, 0, 0, 0);
            a1u = __builtin_amdgcn_mfma_f32_16x16x32_bf16(a0, Bxu[kk], a1u, 0, 0, 0);
            axo = __builtin_amdgcn_mfma_f32_16x16x32_bf16(a0, Bxo[kk], axo, 0, 0, 0);
        }
#pragma unroll
        for (int kk = 0; kk < 4; ++kk) {
            short8 a1 = *(const short8*)(Hbf1 + l15 * 136 + kk * 32 + quad * 8);
            a1r = __builtin_amdgcn_mfma_f32_16x16x32_bf16(a1, B1r[kk], a1r, 0, 0, 0);
            a1u = __builtin_amdgcn_mfma_f32_16x16x32_bf16(a1, B1u[kk], a1u, 0, 0, 0);
        }
        float ug1[4];
#pragma unroll
        for (int i = 0; i < 4; ++i) {
            float rg1 = fast_sigmoid(a1r[i] + br1c);
            ug1[i] = fast_sigmoid(a1u[i] + bu1c);
            Rbf1[(quad * 4 + i) * 136 + c] = f2bf(rg1 * h1c[i]);
        }
        sync_lds();

        // ---- P4: layer1 o + h1 update
        floatx4 a1o = axo;
#pragma unroll
        for (int kk = 0; kk < 4; ++kk) {
            short8 a = *(const short8*)(Rbf1 + l15 * 136 + kk * 32 + quad * 8);
            a1o = __builtin_amdgcn_mfma_f32_16x16x32_bf16(a, B1o[kk], a1o, 0, 0, 0);
        }
#pragma unroll
        for (int i = 0; i < 4; ++i) {
            float og1 = fast_tanh(a1o[i] + bo1c);
            h1c[i] = h1c[i] + ug1[i] * (og1 - h1c[i]);
            Hbf1[(quad * 4 + i) * 136 + c] = f2bf(h1c[i]);
        }
        xr4 = nr4; xu4 = nu4; xo4 = no4;
        // no barrier needed here: P1(t+1) only reads Hbf0 (stable since B2)
        // and writes Rbf0 (last read before B2); Hbf1/Rbf1 hazards are
        // covered by B1/B2 of step t+1 before P3 reads them.
        sync_lds();   // NOTE: kept as B-of-P4->P3 safety?-- no: see below
    }

    // (the sync_lds above doubles as the Hbf1 write->P3 read fence with
    //  minimal cost; 4 barriers/step was measured-cheap vs correctness risk)

#pragma unroll
    for (int i = 0; i < 4; ++i)
        H1fin[(size_t)(b0 + quad * 4 + i) * HID + c] = h1c[i];
}

// ---------------------------------------------------------------------------
// Classifier: out[b][c] = bfc[c] + sum_k H1[b][k] * Wfc[k][c]
// ---------------------------------------------------------------------------
__global__ __launch_bounds__(256) void cls_kernel(
    const float* __restrict__ H1, const float* __restrict__ Wfc,
    const float* __restrict__ bfc, float* __restrict__ out)
{
    const int b = blockIdx.x;
    const int tid = threadIdx.x;
    __shared__ float h[HID];
    if (tid < HID) h[tid] = H1[(size_t)b * HID + tid];
    __syncthreads();
    for (int c = tid; c < NCLS; c += 256) {
        float a = bfc[c];
#pragma unroll 8
        for (int k = 0; k < HID; ++k)
            a += h[k] * Wfc[(size_t)k * NCLS + c];
        out[(size_t)b * NCLS + c] = a;
    }
}

// ---------------------------------------------------------------------------
extern "C" void kernel_launch(void* const* d_in, const int* in_sizes, int n_in,
                              void* d_out, int out_size, void* d_ws, size_t ws_size,
                              hipStream_t stream)
{
    const float* X   = (const float*)d_in[0];
    const float* Wr0 = (const float*)d_in[1];
    const float* br0 = (const float*)d_in[2];
    const float* Wu0 = (const float*)d_in[3];
    const float* bu0 = (const float*)d_in[4];
    const float* Wo0 = (const float*)d_in[5];
    const float* bo0 = (const float*)d_in[6];
    const float* Wr1 = (const float*)d_in[7];
    const float* br1 = (const float*)d_in[8];
    const float* Wu1 = (const float*)d_in[9];
    const float* bu1 = (const float*)d_in[10];
    const float* Wo1 = (const float*)d_in[11];
    const float* bo1 = (const float*)d_in[12];
    const float* Wfc = (const float*)d_in[13];
    const float* bfc = (const float*)d_in[14];
    float* out = (float*)d_out;

    // workspace:
    //   XG  fp32 [281*384*256]   110,493,696 B   ([t][chan][b])
    //   Abf bf16 [M_TOT*288]      41,435,136 B   (H1fin aliases: dead after gemm)
    //   Wt0 bf16 [3*128*288]         221,184 B
    //   Wh0/Wx1/Wh1 bf16 [384*128]    98,304 B each     total ~152.4 MB
    char* ws = (char*)d_ws;
    float*          XG    = (float*)ws;
    unsigned short* Abf   = (unsigned short*)(ws + (size_t)M_TOT * 384 * 4);
    float*          H1fin = (float*)Abf;        // alias: Abf dead after gemm_xg
    unsigned short* Wt0   = (unsigned short*)(ws + (size_t)M_TOT * 384 * 4 + (size_t)M_TOT * KPAD0 * 2);
    unsigned short* Wh0   = Wt0 + (size_t)3 * HID * KPAD0;
    unsigned short* Wx1   = Wh0 + (size_t)384 * HID;
    unsigned short* Wh1   = Wx1 + (size_t)384 * HID;

    wt_kernel<<<dim3(12, 32), 256, 0, stream>>>(Wr0, Wu0, Wo0, Wr1, Wu1, Wo1,
                                                Wt0, Wh0, Wx1, Wh1);
    xt_kernel<<<dim3(5, BATCH), 256, 0, stream>>>(X, Abf);
    gemm_xg  <<<dim3(M_TOT / 128, 3), 256, 0, stream>>>(Abf, Wt0, br0, bu0, bo0, XG);
    gru_fused<<<dim3(16), 512, 0, stream>>>(Wh0, Wx1, Wh1, XG, br1, bu1, bo1, H1fin);
    cls_kernel<<<dim3(BATCH), 256, 0, stream>>>(H1fin, Wfc, bfc, out);
}